// Round 4
// baseline (374.729 us; speedup 1.0000x reference)
//
#include <hip/hip_runtime.h>

typedef __attribute__((ext_vector_type(8))) short short8;
typedef __attribute__((ext_vector_type(4))) float f32x4;
typedef unsigned short ushort_t;

#define MFMA_BF16(A,B,C) __builtin_amdgcn_mfma_f32_16x16x32_bf16(A,B,C,0,0,0)

static constexpr int Bc  = 4;
static constexpr int Nn  = 8000;
static constexpr int DIMc = 256;
static constexpr int NG  = 63;   // ceil(8000/128)

__device__ __forceinline__ unsigned short f2bf(float f){
  unsigned int u = __float_as_uint(f);
  u = (u + 0x7FFFu + ((u >> 16) & 1u)) >> 16;
  return (unsigned short)u;
}
__device__ __forceinline__ uint2 pack4(f32x4 v){
  uint2 r;
  r.x = (unsigned)f2bf(v[0]) | ((unsigned)f2bf(v[1]) << 16);
  r.y = (unsigned)f2bf(v[2]) | ((unsigned)f2bf(v[3]) << 16);
  return r;
}

// ---- X fp32 -> bf16 (vectorized) ----
__global__ __launch_bounds__(256) void cvt_x_kernel(const float* __restrict__ X,
                                                    ushort_t* __restrict__ Xb){
  int i = blockIdx.x * 256 + threadIdx.x;          // 2,048,000 threads, 4 els each
  float4 v = reinterpret_cast<const float4*>(X)[i];
  uint2 o;
  o.x = (unsigned)f2bf(v.x) | ((unsigned)f2bf(v.y) << 16);
  o.y = (unsigned)f2bf(v.z) | ((unsigned)f2bf(v.w) << 16);
  reinterpret_cast<uint2*>(Xb)[i] = o;
}

// ---- merged prep: Wc=[Wq;Wk;Wv] bf16, vgT transpose bf16, kgb bf16, Wpb bf16 ----
__global__ __launch_bounds__(256) void prep_kernel(
    const float* __restrict__ Wq, const float* __restrict__ Wk,
    const float* __restrict__ Wv, const float* __restrict__ Wp,
    const float* __restrict__ kg, const float* __restrict__ vg,
    ushort_t* __restrict__ Wc, ushort_t* __restrict__ vgT,
    ushort_t* __restrict__ kgb, ushort_t* __restrict__ Wpb)
{
  int i = blockIdx.x * 256 + threadIdx.x;          // 294912 total
  if (i < 131072){
    int r = i >> 8, c = i & 255;
    float v;
    if (r < 128)      v = Wq[r * 256 + c];
    else if (r < 256) v = Wk[(r - 128) * 256 + c];
    else              v = Wv[(r - 256) * 256 + c];
    Wc[i] = f2bf(v);
  } else if (i < 196608){
    int j = i - 131072;                            // v_global [8,256,32] -> vgT [8,32,256]
    int c = j & 31, m = (j >> 5) & 255, h = j >> 13;
    vgT[(h * 32 + c) * 256 + m] = f2bf(vg[j]);
  } else if (i < 229376){
    int j = i - 196608;                            // k_global cvt
    kgb[j] = f2bf(kg[j]);
  } else {
    int j = i - 229376;
    Wpb[j] = f2bf(Wp[j]);
  }
}

// ---- QKV projection: rows gathered via idx (output in reordered token space)
// qk: [B,N,256] (q cols 0-127, k cols 128-255); vT: [B,256,N] (transposed v)
__global__ __launch_bounds__(256) void proj_kernel(
    const ushort_t* __restrict__ X, const ushort_t* __restrict__ Wc,
    const int* __restrict__ idx, ushort_t* __restrict__ qk, ushort_t* __restrict__ vT)
{
  const int b  = blockIdx.y;
  const int r0 = blockIdx.x * 16;
  const int tid = threadIdx.x;
  const int w = tid >> 6, l = tid & 63, g4 = l >> 4, q16 = l & 15;
  const int tok = idx[b * Nn + r0 + q16];
  const short8* xrow = reinterpret_cast<const short8*>(X + (size_t)(b * Nn + tok) * DIMc);
  f32x4 acc[8];
  #pragma unroll
  for (int i = 0; i < 8; ++i) acc[i] = f32x4{0.f, 0.f, 0.f, 0.f};
  const int colbase = w * 128;
  #pragma unroll
  for (int kc = 0; kc < 8; ++kc){
    short8 a = xrow[kc * 4 + g4];
    #pragma unroll
    for (int ct = 0; ct < 8; ++ct){
      int col = colbase + ct * 16 + q16;
      short8 bb = *reinterpret_cast<const short8*>(Wc + col * 256 + kc * 32 + g4 * 8);
      acc[ct] = MFMA_BF16(a, bb, acc[ct]);
    }
  }
  if (w < 2){
    #pragma unroll
    for (int ct = 0; ct < 8; ++ct){
      int col = colbase + ct * 16 + q16;
      #pragma unroll
      for (int r = 0; r < 4; ++r){
        int j = r0 + g4 * 4 + r;
        qk[(size_t)(b * Nn + j) * 256 + col] = f2bf(acc[ct][r]);
      }
    }
  } else {
    #pragma unroll
    for (int ct = 0; ct < 8; ++ct){
      int col = colbase - 256 + ct * 16 + q16;
      uint2 pv = pack4(acc[ct]);   // 4 consecutive tokens, same v-column
      *reinterpret_cast<uint2*>(vT + (size_t)(b * 256 + col) * Nn + r0 + g4 * 4) = pv;
    }
  }
}

// ---- fused local-window + global attention ----
// grid (63 groups, 8 heads, 4 batch), 256 thr (4 waves, each wave 2 q-tiles of 16)
__global__ __launch_bounds__(256) void attn_kernel(
    const ushort_t* __restrict__ qk, const ushort_t* __restrict__ vT,
    const ushort_t* __restrict__ kg, const ushort_t* __restrict__ vgT,
    ushort_t* __restrict__ ao)
{
  const int go = blockIdx.x, h = blockIdx.y, b = blockIdx.z;
  const int tid = threadIdx.x;
  const int w = tid >> 6, l = tid & 63, g4 = l >> 4, q16 = l & 15;
  __shared__ __align__(16) ushort_t Plds[4][16][264];
  const f32x4 z4 = {0.f, 0.f, 0.f, 0.f};

  #pragma unroll 1
  for (int qt = 0; qt < 2; ++qt){
    const int qb   = w * 32 + qt * 16;
    const int qpos = go * 128 + qb + q16;
    const int qtok = (qpos < Nn) ? qpos : (2 * Nn - 1) - qpos;  // reflect pad
    short8 qf = {0,0,0,0,0,0,0,0};
    if (g4 < 2)
      qf = *reinterpret_cast<const short8*>(qk + (size_t)(b * Nn + qtok) * 256 + h * 16 + g4 * 8);
    f32x4 res0 = z4, res1 = z4;

    #pragma unroll 1
    for (int pass = 0; pass < 2; ++pass){
      // ---- S^T = K @ Q^T (dq=16 zero-padded to K=32) ----
      f32x4 s[16];
      #pragma unroll
      for (int t = 0; t < 16; ++t){
        short8 kf = {0,0,0,0,0,0,0,0};
        if (g4 < 2){
          if (pass == 0){
            int kp = go * 128 + t * 16 + q16;
            int ktok = (kp < Nn) ? kp : (2 * Nn - 1) - kp;
            kf = *reinterpret_cast<const short8*>(qk + (size_t)(b * Nn + ktok) * 256 + 128 + h * 16 + g4 * 8);
          } else {
            kf = *reinterpret_cast<const short8*>(kg + (size_t)(h * 256 + t * 16 + q16) * 16 + g4 * 8);
          }
        }
        s[t] = MFMA_BF16(kf, qf, z4);
      }
      // ---- softmax over 256 keys for this lane's q (=l&15) ----
      float m = -1e30f;
      #pragma unroll
      for (int t = 0; t < 16; ++t){
        #pragma unroll
        for (int r = 0; r < 4; ++r) m = fmaxf(m, s[t][r]);
      }
      m = fmaxf(m, __shfl_xor(m, 16));
      m = fmaxf(m, __shfl_xor(m, 32));
      float d = 0.f;
      #pragma unroll
      for (int t = 0; t < 16; ++t){
        #pragma unroll
        for (int r = 0; r < 4; ++r){
          float e = __expf((s[t][r] - m) * 0.25f);   // scale=dq^-0.5=0.25 folded here
          s[t][r] = e; d += e;
        }
      }
      d += __shfl_xor(d, 16);
      d += __shfl_xor(d, 32);
      // ---- P -> LDS (bf16) to re-layout as PV B-operand ----
      #pragma unroll
      for (int t = 0; t < 16; ++t){
        uint2 pv = pack4(s[t]);
        *reinterpret_cast<uint2*>(&Plds[w][q16][t * 16 + g4 * 4]) = pv;
      }
      asm volatile("s_waitcnt lgkmcnt(0)" ::: "memory");
      __builtin_amdgcn_sched_barrier(0);
      // ---- O^T = V^T @ P ----
      f32x4 o0 = z4, o1 = z4;
      #pragma unroll
      for (int c = 0; c < 8; ++c){
        short8 pf = *reinterpret_cast<const short8*>(&Plds[w][q16][c * 32 + g4 * 8]);
        #pragma unroll
        for (int dvt = 0; dvt < 2; ++dvt){
          int dv = dvt * 16 + q16;
          short8 vf;
          if (pass == 1){
            vf = *reinterpret_cast<const short8*>(vgT + (size_t)(h * 32 + dv) * 256 + c * 32 + g4 * 8);
          } else {
            int p0 = go * 128 + c * 32 + g4 * 8;
            if (p0 + 7 < Nn){
              vf = *reinterpret_cast<const short8*>(vT + (size_t)(b * 256 + h * 32 + dv) * Nn + p0);
            } else {
              #pragma unroll
              for (int j = 0; j < 8; ++j){
                int p = p0 + j;
                int tk = (p < Nn) ? p : (2 * Nn - 1) - p;
                vf[j] = (short)vT[(size_t)(b * 256 + h * 32 + dv) * Nn + tk];
              }
            }
          }
          if (dvt == 0) o0 = MFMA_BF16(vf, pf, o0);
          else          o1 = MFMA_BF16(vf, pf, o1);
        }
      }
      float invd = 1.0f / d;
      #pragma unroll
      for (int r = 0; r < 4; ++r){ res0[r] += o0[r] * invd; res1[r] += o1[r] * invd; }
    }
    if (qpos < Nn){
      size_t base = (size_t)(b * Nn + qpos) * 256 + h * 32;
      *reinterpret_cast<uint2*>(ao + base + g4 * 4)      = pack4(res0);
      *reinterpret_cast<uint2*>(ao + base + 16 + g4 * 4) = pack4(res1);
    }
  }
}

// ---- final: out[idx[b,j]] = attn[b,j] @ Wp^T   (FP32 output!) ----
__global__ __launch_bounds__(256) void final_kernel(
    const ushort_t* __restrict__ A, const ushort_t* __restrict__ Wp,
    const int* __restrict__ idx, float* __restrict__ out)
{
  const int b  = blockIdx.y;
  const int r0 = blockIdx.x * 16;
  const int tid = threadIdx.x;
  const int w = tid >> 6, l = tid & 63, g4 = l >> 4, q16 = l & 15;
  const short8* arow = reinterpret_cast<const short8*>(A + (size_t)(b * Nn + r0 + q16) * DIMc);
  f32x4 acc[4];
  #pragma unroll
  for (int i = 0; i < 4; ++i) acc[i] = f32x4{0.f, 0.f, 0.f, 0.f};
  const int colbase = w * 64;
  #pragma unroll
  for (int kc = 0; kc < 8; ++kc){
    short8 a = arow[kc * 4 + g4];
    #pragma unroll
    for (int ct = 0; ct < 4; ++ct){
      int col = colbase + ct * 16 + q16;
      short8 bb = *reinterpret_cast<const short8*>(Wp + col * 256 + kc * 32 + g4 * 8);
      acc[ct] = MFMA_BF16(a, bb, acc[ct]);
    }
  }
  int orow[4];
  #pragma unroll
  for (int r = 0; r < 4; ++r) orow[r] = idx[b * Nn + r0 + g4 * 4 + r];
  #pragma unroll
  for (int ct = 0; ct < 4; ++ct){
    int col = colbase + ct * 16 + q16;
    #pragma unroll
    for (int r = 0; r < 4; ++r)
      out[(size_t)(b * Nn + orow[r]) * DIMc + col] = acc[ct][r];
  }
}

extern "C" void kernel_launch(void* const* d_in, const int* in_sizes, int n_in,
                              void* d_out, int out_size, void* d_ws, size_t ws_size,
                              hipStream_t stream)
{
  const float* x   = (const float*)d_in[0];
  const int*   idx = (const int*)d_in[1];
  const float* kg  = (const float*)d_in[2];
  const float* vg  = (const float*)d_in[3];
  const float* Wq  = (const float*)d_in[4];
  const float* Wk  = (const float*)d_in[5];
  const float* Wv  = (const float*)d_in[6];
  const float* Wp  = (const float*)d_in[7];
  float* out = (float*)d_out;

  char* ws = (char*)d_ws;
  size_t off = 0;
  auto alloc = [&](size_t bytes) -> void* {
    void* p = ws + off; off += (bytes + 255) & ~(size_t)255; return p;
  };
  ushort_t* qk   = (ushort_t*)alloc((size_t)Bc * Nn * 256 * 2);  // 16.38 MB
  ushort_t* vT   = (ushort_t*)alloc((size_t)Bc * 256 * Nn * 2);  // 16.38 MB
  ushort_t* attn = (ushort_t*)alloc((size_t)Bc * Nn * 256 * 2);  // 16.38 MB
  ushort_t* Xb   = (ushort_t*)alloc((size_t)Bc * Nn * 256 * 2);  // 16.38 MB
  ushort_t* Wc   = (ushort_t*)alloc((size_t)512 * 256 * 2);      // 256 KB
  ushort_t* vgT  = (ushort_t*)alloc((size_t)8 * 32 * 256 * 2);   // 128 KB
  ushort_t* kgb  = (ushort_t*)alloc((size_t)8 * 256 * 16 * 2);   // 64 KB
  ushort_t* Wpb  = (ushort_t*)alloc((size_t)256 * 256 * 2);      // 128 KB

  hipLaunchKernelGGL(cvt_x_kernel, dim3(8000), dim3(256), 0, stream, x, Xb);
  hipLaunchKernelGGL(prep_kernel,  dim3(1152), dim3(256), 0, stream,
                     Wq, Wk, Wv, Wp, kg, vg, Wc, vgT, kgb, Wpb);
  hipLaunchKernelGGL(proj_kernel,  dim3(500, 4), dim3(256), 0, stream, Xb, Wc, idx, qk, vT);
  hipLaunchKernelGGL(attn_kernel,  dim3(NG, 8, 4), dim3(256), 0, stream, qk, vT, kgb, vgT, attn);
  hipLaunchKernelGGL(final_kernel, dim3(500, 4), dim3(256), 0, stream, attn, Wpb, idx, out);
}

// Round 5
// 372.134 us; speedup vs baseline: 1.0070x; 1.0070x over previous
//
#include <hip/hip_runtime.h>

typedef __attribute__((ext_vector_type(8))) short short8;
typedef __attribute__((ext_vector_type(4))) short short4v;
typedef __attribute__((ext_vector_type(4))) float f32x4;
typedef unsigned short ushort_t;

#define MFMA_BF16_K32(A,B,C) __builtin_amdgcn_mfma_f32_16x16x32_bf16(A,B,C,0,0,0)
#define MFMA_BF16_K16(A,B,C) __builtin_amdgcn_mfma_f32_16x16x16bf16_1k(A,B,C,0,0,0)

static constexpr int Bc  = 4;
static constexpr int Nn  = 8000;
static constexpr int N2  = 8192;   // padded token axis (reflect tail materialized)
static constexpr int DIMc = 256;
static constexpr int NG  = 63;     // ceil(8000/128)

__device__ __forceinline__ unsigned short f2bf(float f){
  unsigned int u = __float_as_uint(f);
  u = (u + 0x7FFFu + ((u >> 16) & 1u)) >> 16;
  return (unsigned short)u;
}
__device__ __forceinline__ uint2 pack4(f32x4 v){
  uint2 r;
  r.x = (unsigned)f2bf(v[0]) | ((unsigned)f2bf(v[1]) << 16);
  r.y = (unsigned)f2bf(v[2]) | ((unsigned)f2bf(v[3]) << 16);
  return r;
}

// ---- X fp32 -> bf16 (vectorized) ----
__global__ __launch_bounds__(256) void cvt_x_kernel(const float* __restrict__ X,
                                                    ushort_t* __restrict__ Xb){
  int i = blockIdx.x * 256 + threadIdx.x;          // 2,048,000 threads, 4 els each
  float4 v = reinterpret_cast<const float4*>(X)[i];
  uint2 o;
  o.x = (unsigned)f2bf(v.x) | ((unsigned)f2bf(v.y) << 16);
  o.y = (unsigned)f2bf(v.z) | ((unsigned)f2bf(v.w) << 16);
  reinterpret_cast<uint2*>(Xb)[i] = o;
}

// ---- merged prep: Wc=[Wq;Wk;Wv] bf16, vgT transpose bf16, kgb bf16, Wpb bf16 ----
__global__ __launch_bounds__(256) void prep_kernel(
    const float* __restrict__ Wq, const float* __restrict__ Wk,
    const float* __restrict__ Wv, const float* __restrict__ Wp,
    const float* __restrict__ kg, const float* __restrict__ vg,
    ushort_t* __restrict__ Wc, ushort_t* __restrict__ vgT,
    ushort_t* __restrict__ kgb, ushort_t* __restrict__ Wpb)
{
  int i = blockIdx.x * 256 + threadIdx.x;          // 294912 total
  if (i < 131072){
    int r = i >> 8, c = i & 255;
    float v;
    if (r < 128)      v = Wq[r * 256 + c];
    else if (r < 256) v = Wk[(r - 128) * 256 + c];
    else              v = Wv[(r - 256) * 256 + c];
    Wc[i] = f2bf(v);
  } else if (i < 196608){
    int j = i - 131072;                            // v_global [8,256,32] -> vgT [8,32,256]
    int c = j & 31, m = (j >> 5) & 255, h = j >> 13;
    vgT[(h * 32 + c) * 256 + m] = f2bf(vg[j]);
  } else if (i < 229376){
    int j = i - 196608;                            // k_global cvt
    kgb[j] = f2bf(kg[j]);
  } else {
    int j = i - 229376;
    Wpb[j] = f2bf(Wp[j]);
  }
}

// ---- QKV projection: rows gathered via idx (output in reordered token space)
// qk: [B,N2,256] (q cols 0-127, k cols 128-255); vT: [B,256,N2] (transposed v)
__global__ __launch_bounds__(256) void proj_kernel(
    const ushort_t* __restrict__ X, const ushort_t* __restrict__ Wc,
    const int* __restrict__ idx, ushort_t* __restrict__ qk, ushort_t* __restrict__ vT)
{
  const int b  = blockIdx.y;
  const int r0 = blockIdx.x * 16;
  const int tid = threadIdx.x;
  const int w = tid >> 6, l = tid & 63, g4 = l >> 4, q16 = l & 15;
  const int tok = idx[b * Nn + r0 + q16];
  const short8* xrow = reinterpret_cast<const short8*>(X + (size_t)(b * Nn + tok) * DIMc);
  f32x4 acc[8];
  #pragma unroll
  for (int i = 0; i < 8; ++i) acc[i] = f32x4{0.f, 0.f, 0.f, 0.f};
  const int colbase = w * 128;
  #pragma unroll
  for (int kc = 0; kc < 8; ++kc){
    short8 a = xrow[kc * 4 + g4];
    #pragma unroll
    for (int ct = 0; ct < 8; ++ct){
      int col = colbase + ct * 16 + q16;
      short8 bb = *reinterpret_cast<const short8*>(Wc + col * 256 + kc * 32 + g4 * 8);
      acc[ct] = MFMA_BF16_K32(a, bb, acc[ct]);
    }
  }
  if (w < 2){
    #pragma unroll
    for (int ct = 0; ct < 8; ++ct){
      int col = colbase + ct * 16 + q16;
      #pragma unroll
      for (int r = 0; r < 4; ++r){
        int j = r0 + g4 * 4 + r;
        qk[(size_t)(b * N2 + j) * 256 + col] = f2bf(acc[ct][r]);
      }
    }
  } else {
    #pragma unroll
    for (int ct = 0; ct < 8; ++ct){
      int col = colbase - 256 + ct * 16 + q16;
      uint2 pv = pack4(acc[ct]);   // 4 consecutive tokens, same v-column
      *reinterpret_cast<uint2*>(vT + (size_t)(b * 256 + col) * N2 + r0 + g4 * 4) = pv;
    }
  }
}

// ---- materialize reflected tail: qk rows [8000,8192), vT cols [8000,8192) ----
__global__ __launch_bounds__(256) void reflect_fill_kernel(
    ushort_t* __restrict__ qk, ushort_t* __restrict__ vT)
{
  int t = blockIdx.x * 256 + threadIdx.x;          // 24576 + 196608 = 221184
  if (t < 24576){
    int b = t / 6144, rem = t % 6144;
    int r = rem >> 5, e = rem & 31;                // r: 0..191, e: uint4 index
    const uint4* src = reinterpret_cast<const uint4*>(qk + (size_t)(b * N2 + 7999 - r) * 256);
    uint4* dst = reinterpret_cast<uint4*>(qk + (size_t)(b * N2 + 8000 + r) * 256);
    dst[e] = src[e];
  } else {
    int u = t - 24576;
    int r = u / 192, i = u % 192;                  // r: 0..1023 (= b*256+vcol)
    vT[(size_t)r * N2 + 8000 + i] = vT[(size_t)r * N2 + 7999 - i];
  }
}

// ---- fused local-window + global attention (K=16 MFMA, P stays in registers) ----
// grid (63 groups, 8 heads, 4 batch), 256 thr (4 waves, each wave 2 q-tiles of 16)
__global__ __launch_bounds__(256, 3) void attn_kernel(
    const ushort_t* __restrict__ qk, const ushort_t* __restrict__ vT,
    const ushort_t* __restrict__ kg, const ushort_t* __restrict__ vgT,
    ushort_t* __restrict__ ao)
{
  const int go = blockIdx.x, h = blockIdx.y, b = blockIdx.z;
  const int tid = threadIdx.x;
  const int w = tid >> 6, l = tid & 63, g4 = l >> 4, q16 = l & 15;
  __shared__ __align__(16) ushort_t Kl[256][16];   // local K window, head slice
  const f32x4 z4 = {0.f, 0.f, 0.f, 0.f};

  // ---- stage local K window (256 tokens x 16 dims, 8 KB) ----
  {
    const uint4* src = reinterpret_cast<const uint4*>(
        qk + (size_t)(b * N2 + go * 128 + tid) * 256 + 128 + h * 16);
    uint4 a0 = src[0], a1 = src[1];
    *reinterpret_cast<uint4*>(&Kl[tid][0]) = a0;
    *reinterpret_cast<uint4*>(&Kl[tid][8]) = a1;
  }
  __syncthreads();

  #pragma unroll 1
  for (int qt = 0; qt < 2; ++qt){
    const int qpos = go * 128 + w * 32 + qt * 16 + q16;   // < 8064, tail pre-reflected
    short4v qf = *reinterpret_cast<const short4v*>(
        qk + (size_t)(b * N2 + qpos) * 256 + h * 16 + g4 * 4);
    f32x4 res0 = z4, res1 = z4;

    #pragma unroll 1
    for (int pass = 0; pass < 2; ++pass){
      // ---- S^T tiles = K @ Q^T (K-dim = 16, exact) ----
      f32x4 s[16];
      #pragma unroll
      for (int t = 0; t < 16; ++t){
        short4v kf;
        if (pass == 0){
          kf = *reinterpret_cast<const short4v*>(&Kl[t * 16 + q16][g4 * 4]);
        } else {
          kf = *reinterpret_cast<const short4v*>(kg + (size_t)(h * 256 + t * 16 + q16) * 16 + g4 * 4);
        }
        s[t] = MFMA_BF16_K16(kf, qf, z4);
      }
      // ---- softmax over 256 keys for this lane's q (=l&15) ----
      float m = -1e30f;
      #pragma unroll
      for (int t = 0; t < 16; ++t){
        #pragma unroll
        for (int r = 0; r < 4; ++r) m = fmaxf(m, s[t][r]);
      }
      m = fmaxf(m, __shfl_xor(m, 16));
      m = fmaxf(m, __shfl_xor(m, 32));
      float d = 0.f;
      #pragma unroll
      for (int t = 0; t < 16; ++t){
        #pragma unroll
        for (int r = 0; r < 4; ++r){
          float e = __expf((s[t][r] - m) * 0.25f);   // scale = dq^-0.5 = 0.25 folded
          s[t][r] = e; d += e;
        }
      }
      d += __shfl_xor(d, 16);
      d += __shfl_xor(d, 32);
      // ---- O^T = V^T @ P : P fragments come straight from s[kk] (layout match) ----
      f32x4 o0 = z4, o1 = z4;
      #pragma unroll
      for (int kk = 0; kk < 16; ++kk){
        short4v pf = __builtin_bit_cast(short4v, pack4(s[kk]));
        short4v vf0, vf1;
        if (pass == 1){
          vf0 = *reinterpret_cast<const short4v*>(vgT + (size_t)(h * 32 + q16) * 256 + kk * 16 + g4 * 4);
          vf1 = *reinterpret_cast<const short4v*>(vgT + (size_t)(h * 32 + 16 + q16) * 256 + kk * 16 + g4 * 4);
        } else {
          size_t base = (size_t)(b * 256 + h * 32 + q16) * N2 + go * 128 + kk * 16 + g4 * 4;
          vf0 = *reinterpret_cast<const short4v*>(vT + base);
          vf1 = *reinterpret_cast<const short4v*>(vT + base + (size_t)16 * N2);
        }
        o0 = MFMA_BF16_K16(vf0, pf, o0);
        o1 = MFMA_BF16_K16(vf1, pf, o1);
      }
      float invd = 1.0f / d;
      #pragma unroll
      for (int r = 0; r < 4; ++r){ res0[r] += o0[r] * invd; res1[r] += o1[r] * invd; }
    }
    if (qpos < Nn){
      size_t base = (size_t)(b * N2 + qpos) * 256 + h * 32;
      *reinterpret_cast<uint2*>(ao + base + g4 * 4)      = pack4(res0);
      *reinterpret_cast<uint2*>(ao + base + 16 + g4 * 4) = pack4(res1);
    }
  }
}

// ---- final: out[idx[b,j]] = attn[b,j] @ Wp^T   (FP32 output) ----
__global__ __launch_bounds__(256) void final_kernel(
    const ushort_t* __restrict__ A, const ushort_t* __restrict__ Wp,
    const int* __restrict__ idx, float* __restrict__ out)
{
  const int b  = blockIdx.y;
  const int r0 = blockIdx.x * 16;
  const int tid = threadIdx.x;
  const int w = tid >> 6, l = tid & 63, g4 = l >> 4, q16 = l & 15;
  const short8* arow = reinterpret_cast<const short8*>(A + (size_t)(b * N2 + r0 + q16) * DIMc);
  f32x4 acc[4];
  #pragma unroll
  for (int i = 0; i < 4; ++i) acc[i] = f32x4{0.f, 0.f, 0.f, 0.f};
  const int colbase = w * 64;
  #pragma unroll
  for (int kc = 0; kc < 8; ++kc){
    short8 a = arow[kc * 4 + g4];
    #pragma unroll
    for (int ct = 0; ct < 4; ++ct){
      int col = colbase + ct * 16 + q16;
      short8 bb = *reinterpret_cast<const short8*>(Wp + col * 256 + kc * 32 + g4 * 8);
      acc[ct] = MFMA_BF16_K32(a, bb, acc[ct]);
    }
  }
  int orow[4];
  #pragma unroll
  for (int r = 0; r < 4; ++r) orow[r] = idx[b * Nn + r0 + g4 * 4 + r];
  #pragma unroll
  for (int ct = 0; ct < 4; ++ct){
    int col = colbase + ct * 16 + q16;
    #pragma unroll
    for (int r = 0; r < 4; ++r)
      out[(size_t)(b * Nn + orow[r]) * DIMc + col] = acc[ct][r];
  }
}

extern "C" void kernel_launch(void* const* d_in, const int* in_sizes, int n_in,
                              void* d_out, int out_size, void* d_ws, size_t ws_size,
                              hipStream_t stream)
{
  const float* x   = (const float*)d_in[0];
  const int*   idx = (const int*)d_in[1];
  const float* kg  = (const float*)d_in[2];
  const float* vg  = (const float*)d_in[3];
  const float* Wq  = (const float*)d_in[4];
  const float* Wk  = (const float*)d_in[5];
  const float* Wv  = (const float*)d_in[6];
  const float* Wp  = (const float*)d_in[7];
  float* out = (float*)d_out;

  char* ws = (char*)d_ws;
  size_t off = 0;
  auto alloc = [&](size_t bytes) -> void* {
    void* p = ws + off; off += (bytes + 255) & ~(size_t)255; return p;
  };
  ushort_t* qk   = (ushort_t*)alloc((size_t)Bc * N2 * 256 * 2);  // 16.78 MB
  ushort_t* vT   = (ushort_t*)alloc((size_t)Bc * 256 * N2 * 2);  // 16.78 MB
  ushort_t* attn = (ushort_t*)alloc((size_t)Bc * N2 * 256 * 2);  // 16.78 MB
  ushort_t* Xb   = (ushort_t*)alloc((size_t)Bc * Nn * 256 * 2);  // 16.38 MB
  ushort_t* Wc   = (ushort_t*)alloc((size_t)512 * 256 * 2);      // 256 KB
  ushort_t* vgT  = (ushort_t*)alloc((size_t)8 * 32 * 256 * 2);   // 128 KB
  ushort_t* kgb  = (ushort_t*)alloc((size_t)8 * 256 * 16 * 2);   // 64 KB
  ushort_t* Wpb  = (ushort_t*)alloc((size_t)256 * 256 * 2);      // 128 KB

  hipLaunchKernelGGL(cvt_x_kernel, dim3(8000), dim3(256), 0, stream, x, Xb);
  hipLaunchKernelGGL(prep_kernel,  dim3(1152), dim3(256), 0, stream,
                     Wq, Wk, Wv, Wp, kg, vg, Wc, vgT, kgb, Wpb);
  hipLaunchKernelGGL(proj_kernel,  dim3(500, 4), dim3(256), 0, stream, Xb, Wc, idx, qk, vT);
  hipLaunchKernelGGL(reflect_fill_kernel, dim3(864), dim3(256), 0, stream, qk, vT);
  hipLaunchKernelGGL(attn_kernel,  dim3(NG, 8, 4), dim3(256), 0, stream, qk, vT, kgb, vgT, attn);
  hipLaunchKernelGGL(final_kernel, dim3(500, 4), dim3(256), 0, stream, attn, Wpb, idx, out);
}

// Round 6
// 262.074 us; speedup vs baseline: 1.4299x; 1.4200x over previous
//
#include <hip/hip_runtime.h>

typedef __attribute__((ext_vector_type(8))) short short8;
typedef __attribute__((ext_vector_type(4))) short short4v;
typedef __attribute__((ext_vector_type(4))) float f32x4;
typedef unsigned short ushort_t;

#define MFMA_BF16_K32(A,B,C) __builtin_amdgcn_mfma_f32_16x16x32_bf16(A,B,C,0,0,0)
#define MFMA_BF16_K16(A,B,C) __builtin_amdgcn_mfma_f32_16x16x16bf16_1k(A,B,C,0,0,0)

static constexpr int Bc  = 4;
static constexpr int Nn  = 8000;
static constexpr int N2  = 8192;   // padded token axis (reflect tail materialized)
static constexpr int DIMc = 256;
static constexpr int NG  = 63;     // ceil(8000/128)

__device__ __forceinline__ unsigned short f2bf(float f){
  unsigned int u = __float_as_uint(f);
  u = (u + 0x7FFFu + ((u >> 16) & 1u)) >> 16;
  return (unsigned short)u;
}
__device__ __forceinline__ uint2 pack4(f32x4 v){
  uint2 r;
  r.x = (unsigned)f2bf(v[0]) | ((unsigned)f2bf(v[1]) << 16);
  r.y = (unsigned)f2bf(v[2]) | ((unsigned)f2bf(v[3]) << 16);
  return r;
}

// ---- X fp32 -> bf16 (vectorized) ----
__global__ __launch_bounds__(256) void cvt_x_kernel(const float* __restrict__ X,
                                                    ushort_t* __restrict__ Xb){
  int i = blockIdx.x * 256 + threadIdx.x;
  float4 v = reinterpret_cast<const float4*>(X)[i];
  uint2 o;
  o.x = (unsigned)f2bf(v.x) | ((unsigned)f2bf(v.y) << 16);
  o.y = (unsigned)f2bf(v.z) | ((unsigned)f2bf(v.w) << 16);
  reinterpret_cast<uint2*>(Xb)[i] = o;
}

// ---- merged prep: Wc=[Wq;Wk;Wv] bf16, vgT transpose bf16, kgb bf16, Wpb bf16 ----
__global__ __launch_bounds__(256) void prep_kernel(
    const float* __restrict__ Wq, const float* __restrict__ Wk,
    const float* __restrict__ Wv, const float* __restrict__ Wp,
    const float* __restrict__ kg, const float* __restrict__ vg,
    ushort_t* __restrict__ Wc, ushort_t* __restrict__ vgT,
    ushort_t* __restrict__ kgb, ushort_t* __restrict__ Wpb)
{
  int i = blockIdx.x * 256 + threadIdx.x;          // 294912 total
  if (i < 131072){
    int r = i >> 8, c = i & 255;
    float v;
    if (r < 128)      v = Wq[r * 256 + c];
    else if (r < 256) v = Wk[(r - 128) * 256 + c];
    else              v = Wv[(r - 256) * 256 + c];
    Wc[i] = f2bf(v);
  } else if (i < 196608){
    int j = i - 131072;                            // v_global [8,256,32] -> vgT [8,32,256]
    int c = j & 31, m = (j >> 5) & 255, h = j >> 13;
    vgT[(h * 32 + c) * 256 + m] = f2bf(vg[j]);
  } else if (i < 229376){
    int j = i - 196608;                            // k_global cvt
    kgb[j] = f2bf(kg[j]);
  } else {
    int j = i - 229376;
    Wpb[j] = f2bf(Wp[j]);
  }
}

// ---- QKV projection (rows gathered via idx, outputs in reordered token space)
// qh/kh: [B][H][N2][16] head-major; vT: [B][256][N2]
__global__ __launch_bounds__(256) void proj_kernel(
    const ushort_t* __restrict__ X, const ushort_t* __restrict__ Wc,
    const int* __restrict__ idx, ushort_t* __restrict__ qh,
    ushort_t* __restrict__ kh, ushort_t* __restrict__ vT)
{
  const int b  = blockIdx.y;
  const int r0 = blockIdx.x * 16;
  const int tid = threadIdx.x;
  const int w = tid >> 6, l = tid & 63, g4 = l >> 4, q16 = l & 15;
  const int tok = idx[b * Nn + r0 + q16];
  const short8* xrow = reinterpret_cast<const short8*>(X + (size_t)(b * Nn + tok) * DIMc);
  f32x4 acc[8];
  #pragma unroll
  for (int i = 0; i < 8; ++i) acc[i] = f32x4{0.f, 0.f, 0.f, 0.f};
  const int colbase = w * 128;
  #pragma unroll
  for (int kc = 0; kc < 8; ++kc){
    short8 a = xrow[kc * 4 + g4];
    #pragma unroll
    for (int ct = 0; ct < 8; ++ct){
      int col = colbase + ct * 16 + q16;
      short8 bb = *reinterpret_cast<const short8*>(Wc + col * 256 + kc * 32 + g4 * 8);
      acc[ct] = MFMA_BF16_K32(a, bb, acc[ct]);
    }
  }
  if (w < 2){
    ushort_t* dst = (w == 0) ? qh : kh;            // head ct, dim q16
    #pragma unroll
    for (int ct = 0; ct < 8; ++ct){
      #pragma unroll
      for (int r = 0; r < 4; ++r){
        int j = r0 + g4 * 4 + r;
        dst[((size_t)(b * 8 + ct) * N2 + j) * 16 + q16] = f2bf(acc[ct][r]);
      }
    }
  } else {
    #pragma unroll
    for (int ct = 0; ct < 8; ++ct){
      int col = colbase - 256 + ct * 16 + q16;
      uint2 pv = pack4(acc[ct]);   // 4 consecutive tokens, same v-column
      *reinterpret_cast<uint2*>(vT + (size_t)(b * 256 + col) * N2 + r0 + g4 * 4) = pv;
    }
  }
}

// ---- materialize reflected tails: qh/kh rows [8000,8192), vT cols [8000,8192) ----
__global__ __launch_bounds__(256) void reflect_fill_kernel(
    ushort_t* __restrict__ qh, ushort_t* __restrict__ kh, ushort_t* __restrict__ vT)
{
  int t = blockIdx.x * 256 + threadIdx.x;          // 24576 + 196608 = 221184
  if (t < 24576){
    int e = t & 1;                                 // uint4 half of a 32B row
    int r = (t >> 1) % 192;
    int p = (t >> 1) / 192;                        // 0..63 = b*16 + (buf*8+h)
    int b = p >> 4, q = p & 15;
    ushort_t* base = (q < 8) ? qh : kh;
    int h = q & 7;
    size_t plane = (size_t)(b * 8 + h) * N2 * 16;
    const uint4* src = reinterpret_cast<const uint4*>(base + plane + (size_t)(7999 - r) * 16);
    uint4*       dst = reinterpret_cast<uint4*>(base + plane + (size_t)(8000 + r) * 16);
    dst[e] = src[e];
  } else {
    int u = t - 24576;
    int r = u / 192, i = u % 192;                  // r: 0..1023 (= b*256+vcol)
    vT[(size_t)r * N2 + 8000 + i] = vT[(size_t)r * N2 + 7999 - i];
  }
}

// ---- fused local-window + global attention: all-dense accesses, no LDS ----
// grid (63, 8, 4), 256 thr (4 waves, each wave 2 q-tiles of 16)
__global__ __launch_bounds__(256) void attn_kernel(
    const ushort_t* __restrict__ qh, const ushort_t* __restrict__ kh,
    const ushort_t* __restrict__ vT,
    const ushort_t* __restrict__ kg, const ushort_t* __restrict__ vgT,
    ushort_t* __restrict__ aoh)
{
  const int go = blockIdx.x, h = blockIdx.y, b = blockIdx.z;
  const int tid = threadIdx.x;
  const int w = tid >> 6, l = tid & 63, g4 = l >> 4, q16 = l & 15;
  const f32x4 z4 = {0.f, 0.f, 0.f, 0.f};
  const size_t bh = (size_t)(b * 8 + h);
  const ushort_t* Kloc = kh + (bh * N2 + go * 128) * 16;        // 256 tok x 16, dense
  const ushort_t* Qpl  = qh + bh * N2 * 16;
  const ushort_t* Vloc = vT + (size_t)(b * 256 + h * 32) * N2 + go * 128;
  const ushort_t* Kg   = kg + (size_t)h * 256 * 16;
  const ushort_t* Vg   = vgT + (size_t)h * 32 * 256;

  #pragma unroll 1
  for (int qt = 0; qt < 2; ++qt){
    const int qpos = go * 128 + w * 32 + qt * 16 + q16;          // < 8064 (tail prefilled)
    short4v qf = *reinterpret_cast<const short4v*>(Qpl + (size_t)qpos * 16 + g4 * 4);
    f32x4 res0 = z4, res1 = z4;

    #pragma unroll 1
    for (int pass = 0; pass < 2; ++pass){
      // ---- S^T tiles = K @ Q^T (K-dim = 16 exact) ----
      f32x4 s[16];
      #pragma unroll
      for (int t = 0; t < 16; ++t){
        const ushort_t* kp = (pass == 0)
            ? (Kloc + (size_t)(t * 16 + q16) * 16 + g4 * 4)
            : (Kg   + (size_t)(t * 16 + q16) * 16 + g4 * 4);
        short4v kf = *reinterpret_cast<const short4v*>(kp);
        s[t] = MFMA_BF16_K16(kf, qf, z4);
      }
      // ---- softmax over 256 keys for this lane's q (=l&15) ----
      float m = -1e30f;
      #pragma unroll
      for (int t = 0; t < 16; ++t){
        #pragma unroll
        for (int r = 0; r < 4; ++r) m = fmaxf(m, s[t][r]);
      }
      m = fmaxf(m, __shfl_xor(m, 16));
      m = fmaxf(m, __shfl_xor(m, 32));
      float d = 0.f;
      #pragma unroll
      for (int t = 0; t < 16; ++t){
        #pragma unroll
        for (int r = 0; r < 4; ++r){
          float e = __expf((s[t][r] - m) * 0.25f);   // scale = dq^-0.5 folded
          s[t][r] = e; d += e;
        }
      }
      d += __shfl_xor(d, 16);
      d += __shfl_xor(d, 32);
      // ---- O^T = V^T @ P, K=32 MFMA; P packed straight from s[] registers.
      // Both A (V) and B (P) use the same k-permutation: token(g4,j) =
      // 32*t2 + (j>>2)*16 + g4*4 + (j&3)  -> permutation cancels in the dot.
      f32x4 o0 = z4, o1 = z4;
      #pragma unroll
      for (int t2 = 0; t2 < 8; ++t2){
        uint2 plo = pack4(s[2 * t2]);
        uint2 phi = pack4(s[2 * t2 + 1]);
        uint4 pu; pu.x = plo.x; pu.y = plo.y; pu.z = phi.x; pu.w = phi.y;
        short8 pf = __builtin_bit_cast(short8, pu);
        const ushort_t* v0;
        size_t rstride;
        if (pass == 0){ v0 = Vloc + (size_t)q16 * N2 + t2 * 32 + g4 * 4; rstride = (size_t)16 * N2; }
        else          { v0 = Vg   + (size_t)q16 * 256 + t2 * 32 + g4 * 4; rstride = 16 * 256; }
        uint2 lo0 = *reinterpret_cast<const uint2*>(v0);
        uint2 hi0 = *reinterpret_cast<const uint2*>(v0 + 16);
        uint2 lo1 = *reinterpret_cast<const uint2*>(v0 + rstride);
        uint2 hi1 = *reinterpret_cast<const uint2*>(v0 + rstride + 16);
        uint4 vu0; vu0.x = lo0.x; vu0.y = lo0.y; vu0.z = hi0.x; vu0.w = hi0.y;
        uint4 vu1; vu1.x = lo1.x; vu1.y = lo1.y; vu1.z = hi1.x; vu1.w = hi1.y;
        o0 = MFMA_BF16_K32(__builtin_bit_cast(short8, vu0), pf, o0);
        o1 = MFMA_BF16_K32(__builtin_bit_cast(short8, vu1), pf, o1);
      }
      float invd = 1.0f / d;
      #pragma unroll
      for (int r = 0; r < 4; ++r){ res0[r] += o0[r] * invd; res1[r] += o1[r] * invd; }
    }
    if (qpos < Nn){
      size_t base = (bh * N2 + qpos) * 32;         // lane owns token qpos, dims g4*4..
      *reinterpret_cast<uint2*>(aoh + base + g4 * 4)      = pack4(res0);
      *reinterpret_cast<uint2*>(aoh + base + 16 + g4 * 4) = pack4(res1);
    }
  }
}

// ---- final: out[idx[b,j]] = attn[b,j] @ Wp^T   (FP32 output) ----
__global__ __launch_bounds__(256) void final_kernel(
    const ushort_t* __restrict__ A, const ushort_t* __restrict__ Wp,
    const int* __restrict__ idx, float* __restrict__ out)
{
  const int b  = blockIdx.y;
  const int r0 = blockIdx.x * 16;
  const int tid = threadIdx.x;
  const int w = tid >> 6, l = tid & 63, g4 = l >> 4, q16 = l & 15;
  const int tok = r0 + q16;
  f32x4 acc[4];
  #pragma unroll
  for (int i = 0; i < 4; ++i) acc[i] = f32x4{0.f, 0.f, 0.f, 0.f};
  const int colbase = w * 64;
  #pragma unroll
  for (int kc = 0; kc < 8; ++kc){                  // k = kc*32 + g4*8 + j  (head kc)
    short8 a = *reinterpret_cast<const short8*>(
        A + ((size_t)(b * 8 + kc) * N2 + tok) * 32 + g4 * 8);
    #pragma unroll
    for (int ct = 0; ct < 4; ++ct){
      int col = colbase + ct * 16 + q16;
      short8 bb = *reinterpret_cast<const short8*>(Wp + col * 256 + kc * 32 + g4 * 8);
      acc[ct] = MFMA_BF16_K32(a, bb, acc[ct]);
    }
  }
  int orow[4];
  #pragma unroll
  for (int r = 0; r < 4; ++r) orow[r] = idx[b * Nn + r0 + g4 * 4 + r];
  #pragma unroll
  for (int ct = 0; ct < 4; ++ct){
    int col = colbase + ct * 16 + q16;
    #pragma unroll
    for (int r = 0; r < 4; ++r)
      out[(size_t)(b * Nn + orow[r]) * DIMc + col] = acc[ct][r];
  }
}

extern "C" void kernel_launch(void* const* d_in, const int* in_sizes, int n_in,
                              void* d_out, int out_size, void* d_ws, size_t ws_size,
                              hipStream_t stream)
{
  const float* x   = (const float*)d_in[0];
  const int*   idx = (const int*)d_in[1];
  const float* kg  = (const float*)d_in[2];
  const float* vg  = (const float*)d_in[3];
  const float* Wq  = (const float*)d_in[4];
  const float* Wk  = (const float*)d_in[5];
  const float* Wv  = (const float*)d_in[6];
  const float* Wp  = (const float*)d_in[7];
  float* out = (float*)d_out;

  char* ws = (char*)d_ws;
  size_t off = 0;
  auto alloc = [&](size_t bytes) -> void* {
    void* p = ws + off; off += (bytes + 255) & ~(size_t)255; return p;
  };
  ushort_t* qh   = (ushort_t*)alloc((size_t)Bc * 8 * N2 * 16 * 2);  // 8.39 MB
  ushort_t* kh   = (ushort_t*)alloc((size_t)Bc * 8 * N2 * 16 * 2);  // 8.39 MB
  ushort_t* vT   = (ushort_t*)alloc((size_t)Bc * 256 * N2 * 2);     // 16.78 MB
  ushort_t* aoh  = (ushort_t*)alloc((size_t)Bc * 8 * N2 * 32 * 2);  // 16.78 MB
  ushort_t* Xb   = (ushort_t*)alloc((size_t)Bc * Nn * 256 * 2);     // 16.38 MB
  ushort_t* Wc   = (ushort_t*)alloc((size_t)512 * 256 * 2);         // 256 KB
  ushort_t* vgT  = (ushort_t*)alloc((size_t)8 * 32 * 256 * 2);      // 128 KB
  ushort_t* kgb  = (ushort_t*)alloc((size_t)8 * 256 * 16 * 2);      // 64 KB
  ushort_t* Wpb  = (ushort_t*)alloc((size_t)256 * 256 * 2);         // 128 KB

  hipLaunchKernelGGL(cvt_x_kernel, dim3(8000), dim3(256), 0, stream, x, Xb);
  hipLaunchKernelGGL(prep_kernel,  dim3(1152), dim3(256), 0, stream,
                     Wq, Wk, Wv, Wp, kg, vg, Wc, vgT, kgb, Wpb);
  hipLaunchKernelGGL(proj_kernel,  dim3(500, 4), dim3(256), 0, stream, Xb, Wc, idx, qh, kh, vT);
  hipLaunchKernelGGL(reflect_fill_kernel, dim3(864), dim3(256), 0, stream, qh, kh, vT);
  hipLaunchKernelGGL(attn_kernel,  dim3(NG, 8, 4), dim3(256), 0, stream, qh, kh, vT, kgb, vgT, aoh);
  hipLaunchKernelGGL(final_kernel, dim3(500, 4), dim3(256), 0, stream, aoh, Wpb, idx, out);
}

// Round 7
// 164.203 us; speedup vs baseline: 2.2821x; 1.5960x over previous
//
#include <hip/hip_runtime.h>

typedef __attribute__((ext_vector_type(8))) short short8;
typedef __attribute__((ext_vector_type(4))) short short4v;
typedef __attribute__((ext_vector_type(4))) float f32x4;
typedef unsigned short ushort_t;

#define MFMA_BF16_K32(A,B,C) __builtin_amdgcn_mfma_f32_16x16x32_bf16(A,B,C,0,0,0)
#define MFMA_BF16_K16(A,B,C) __builtin_amdgcn_mfma_f32_16x16x16bf16_1k(A,B,C,0,0,0)

static constexpr int Bc  = 4;
static constexpr int Nn  = 8000;
static constexpr int N2  = 8192;
static constexpr int DIMc = 256;
static constexpr int NG  = 63;

__device__ __forceinline__ unsigned short f2bf(float f){
  unsigned int u = __float_as_uint(f);
  u = (u + 0x7FFFu + ((u >> 16) & 1u)) >> 16;
  return (unsigned short)u;
}
__device__ __forceinline__ uint2 pack4(f32x4 v){
  uint2 r;
  r.x = (unsigned)f2bf(v[0]) | ((unsigned)f2bf(v[1]) << 16);
  r.y = (unsigned)f2bf(v[2]) | ((unsigned)f2bf(v[3]) << 16);
  return r;
}
__device__ __forceinline__ unsigned cvtpk(float lo, float hi){
  unsigned r;
  asm("v_cvt_pk_bf16_f32 %0, %1, %2" : "=v"(r) : "v"(lo), "v"(hi));
  return r;
}
// permuted position of token t within its 32-block (V layout for dense PV loads)
__device__ __forceinline__ int vperm(int t){
  return (t & ~31) | (((t >> 2) & 3) * 8 + ((t >> 4) & 1) * 4 + (t & 3));
}

// ---- X fp32 -> bf16 ----
__global__ __launch_bounds__(256) void cvt_x_kernel(const float* __restrict__ X,
                                                    ushort_t* __restrict__ Xb){
  int i = blockIdx.x * 256 + threadIdx.x;
  float4 v = reinterpret_cast<const float4*>(X)[i];
  uint2 o;
  o.x = (unsigned)f2bf(v.x) | ((unsigned)f2bf(v.y) << 16);
  o.y = (unsigned)f2bf(v.z) | ((unsigned)f2bf(v.w) << 16);
  reinterpret_cast<uint2*>(Xb)[i] = o;
}

// ---- prep: Wc=[Wq;Wk;Wv], vgT (token-permuted), kgb, Wpb ----
__global__ __launch_bounds__(256) void prep_kernel(
    const float* __restrict__ Wq, const float* __restrict__ Wk,
    const float* __restrict__ Wv, const float* __restrict__ Wp,
    const float* __restrict__ kg, const float* __restrict__ vg,
    ushort_t* __restrict__ Wc, ushort_t* __restrict__ vgT,
    ushort_t* __restrict__ kgb, ushort_t* __restrict__ Wpb)
{
  int i = blockIdx.x * 256 + threadIdx.x;          // 294912 total
  if (i < 131072){
    int r = i >> 8, c = i & 255;
    float v;
    if (r < 128)      v = Wq[r * 256 + c];
    else if (r < 256) v = Wk[(r - 128) * 256 + c];
    else              v = Wv[(r - 256) * 256 + c];
    Wc[i] = f2bf(v);
  } else if (i < 196608){
    int j = i - 131072;                            // vg [8,256,32] -> vgT [8,32,256] permuted
    int c = j & 31, m = (j >> 5) & 255, h = j >> 13;
    vgT[(h * 32 + c) * 256 + vperm(m)] = f2bf(vg[j]);
  } else if (i < 229376){
    int j = i - 196608;
    kgb[j] = f2bf(kg[j]);
  } else {
    int j = i - 229376;
    Wpb[j] = f2bf(Wp[j]);
  }
}

// ---- QKV projection, M=64 per block. qh/kh: [B][H][N2][16]; vT: [B][256][N2] (perm) ----
__global__ __launch_bounds__(256) void proj_kernel(
    const ushort_t* __restrict__ X, const ushort_t* __restrict__ Wc,
    const int* __restrict__ idx, ushort_t* __restrict__ qh,
    ushort_t* __restrict__ kh, ushort_t* __restrict__ vT)
{
  const int b  = blockIdx.y;
  const int r0 = blockIdx.x * 64;
  const int tid = threadIdx.x;
  const int w = tid >> 6, l = tid & 63, g4 = l >> 4, q16 = l & 15;
  const short8* xrow[4];
  #pragma unroll
  for (int mt = 0; mt < 4; ++mt){
    int tok = idx[b * Nn + r0 + mt * 16 + q16];
    xrow[mt] = reinterpret_cast<const short8*>(X + (size_t)(b * Nn + tok) * DIMc);
  }
  f32x4 acc[4][8];
  #pragma unroll
  for (int mt = 0; mt < 4; ++mt)
    #pragma unroll
    for (int ct = 0; ct < 8; ++ct) acc[mt][ct] = f32x4{0.f, 0.f, 0.f, 0.f};
  const int colbase = w * 128;
  #pragma unroll
  for (int kc = 0; kc < 8; ++kc){
    short8 a[4];
    #pragma unroll
    for (int mt = 0; mt < 4; ++mt) a[mt] = xrow[mt][kc * 4 + g4];
    #pragma unroll
    for (int ct = 0; ct < 8; ++ct){
      int col = colbase + ct * 16 + q16;
      short8 bb = *reinterpret_cast<const short8*>(Wc + col * 256 + kc * 32 + g4 * 8);
      #pragma unroll
      for (int mt = 0; mt < 4; ++mt) acc[mt][ct] = MFMA_BF16_K32(a[mt], bb, acc[mt][ct]);
    }
  }
  if (w < 2){
    ushort_t* dst = (w == 0) ? qh : kh;
    #pragma unroll
    for (int ct = 0; ct < 8; ++ct){
      #pragma unroll
      for (int mt = 0; mt < 4; ++mt){
        #pragma unroll
        for (int r = 0; r < 4; ++r){
          int j = r0 + mt * 16 + g4 * 4 + r;
          dst[((size_t)(b * 8 + ct) * N2 + j) * 16 + q16] = f2bf(acc[mt][ct][r]);
        }
      }
    }
  } else {
    #pragma unroll
    for (int ct = 0; ct < 8; ++ct){
      int col = colbase - 256 + ct * 16 + q16;
      #pragma unroll
      for (int mt = 0; mt < 4; ++mt){
        int jb = r0 + (mt >> 1) * 32 + g4 * 8 + (mt & 1) * 4;   // permuted, 4 consecutive
        *reinterpret_cast<uint2*>(vT + (size_t)(b * 256 + col) * N2 + jb) = pack4(acc[mt][ct]);
      }
    }
  }
}

// ---- reflected tails: qh/kh rows [8000,8192), vT (permuted) cols [8000,8192) ----
__global__ __launch_bounds__(256) void reflect_fill_kernel(
    ushort_t* __restrict__ qh, ushort_t* __restrict__ kh, ushort_t* __restrict__ vT)
{
  int t = blockIdx.x * 256 + threadIdx.x;          // 24576 + 196608 = 221184
  if (t < 24576){
    int e = t & 1;
    int r = (t >> 1) % 192;
    int p = (t >> 1) / 192;
    int b = p >> 4, q = p & 15;
    ushort_t* base = (q < 8) ? qh : kh;
    int h = q & 7;
    size_t plane = (size_t)(b * 8 + h) * N2 * 16;
    const uint4* src = reinterpret_cast<const uint4*>(base + plane + (size_t)(7999 - r) * 16);
    uint4*       dst = reinterpret_cast<uint4*>(base + plane + (size_t)(8000 + r) * 16);
    dst[e] = src[e];
  } else {
    int u = t - 24576;
    int r = u / 192, i2 = u % 192;
    vT[(size_t)r * N2 + vperm(8000 + i2)] = vT[(size_t)r * N2 + vperm(7999 - i2)];
  }
}

// ---- fused local + global attention: dense loads, tree softmax, V prefetch ----
__global__ __launch_bounds__(256) void attn_kernel(
    const ushort_t* __restrict__ qh, const ushort_t* __restrict__ kh,
    const ushort_t* __restrict__ vT,
    const ushort_t* __restrict__ kg, const ushort_t* __restrict__ vgT,
    ushort_t* __restrict__ aoh)
{
  const int go = blockIdx.x, h = blockIdx.y, b = blockIdx.z;
  const int tid = threadIdx.x;
  const int w = tid >> 6, l = tid & 63, g4 = l >> 4, q16 = l & 15;
  const f32x4 z4 = {0.f, 0.f, 0.f, 0.f};
  const float SC2 = 0.36067376022224085f;          // 0.25 * log2(e)
  const size_t bh = (size_t)(b * 8 + h);
  const ushort_t* Kloc = kh + (bh * N2 + go * 128) * 16;
  const ushort_t* Qpl  = qh + bh * N2 * 16;
  const ushort_t* Vloc = vT + (size_t)(b * 256 + h * 32) * N2 + go * 128;
  const ushort_t* Kg   = kg + (size_t)h * 256 * 16;
  const ushort_t* Vg   = vgT + (size_t)h * 32 * 256;

  #pragma unroll 1
  for (int qt = 0; qt < 2; ++qt){
    const int qpos = go * 128 + w * 32 + qt * 16 + q16;
    short4v qf = *reinterpret_cast<const short4v*>(Qpl + (size_t)qpos * 16 + g4 * 4);
    f32x4 res0 = z4, res1 = z4;

    #pragma unroll 1
    for (int pass = 0; pass < 2; ++pass){
      // ---- S^T = K @ Q^T (16 tiles) ----
      const ushort_t* kbase = (pass == 0) ? Kloc : Kg;
      f32x4 s[16];
      #pragma unroll
      for (int t = 0; t < 16; ++t){
        short4v kf = *reinterpret_cast<const short4v*>(
            kbase + (size_t)(t * 16 + q16) * 16 + g4 * 4);
        s[t] = MFMA_BF16_K16(kf, qf, z4);
      }
      // ---- prefetch V (dense uint4 per t2, latency hides under softmax) ----
      const ushort_t* v0;
      size_t rstride;
      if (pass == 0){ v0 = Vloc + (size_t)q16 * N2 + g4 * 8;  rstride = (size_t)16 * N2; }
      else          { v0 = Vg   + (size_t)q16 * 256 + g4 * 8; rstride = (size_t)16 * 256; }
      uint4 va[8], vb[8];
      #pragma unroll
      for (int t2 = 0; t2 < 8; ++t2){
        va[t2] = *reinterpret_cast<const uint4*>(v0 + t2 * 32);
        vb[t2] = *reinterpret_cast<const uint4*>(v0 + rstride + t2 * 32);
      }
      // ---- softmax: tree max, exp2, tree sum ----
      float tm[16];
      #pragma unroll
      for (int t = 0; t < 16; ++t)
        tm[t] = fmaxf(fmaxf(s[t][0], s[t][1]), fmaxf(s[t][2], s[t][3]));
      #pragma unroll
      for (int st = 8; st >= 1; st >>= 1)
        #pragma unroll
        for (int i2 = 0; i2 < st; ++i2) tm[i2] = fmaxf(tm[i2], tm[i2 + st]);
      float m = tm[0];
      m = fmaxf(m, __shfl_xor(m, 16));
      m = fmaxf(m, __shfl_xor(m, 32));
      float msc = m * SC2;
      f32x4 dp = z4;
      uint2 p[16];
      #pragma unroll
      for (int t = 0; t < 16; ++t){
        float e0 = __builtin_exp2f(__builtin_fmaf(s[t][0], SC2, -msc));
        float e1 = __builtin_exp2f(__builtin_fmaf(s[t][1], SC2, -msc));
        float e2 = __builtin_exp2f(__builtin_fmaf(s[t][2], SC2, -msc));
        float e3 = __builtin_exp2f(__builtin_fmaf(s[t][3], SC2, -msc));
        dp[0] += e0; dp[1] += e1; dp[2] += e2; dp[3] += e3;
        p[t].x = cvtpk(e0, e1); p[t].y = cvtpk(e2, e3);
      }
      float d = (dp[0] + dp[1]) + (dp[2] + dp[3]);
      d += __shfl_xor(d, 16);
      d += __shfl_xor(d, 32);
      // ---- O^T = V^T @ P  (K=32, permutation cancels between A and B) ----
      f32x4 o0 = z4, o1 = z4;
      #pragma unroll
      for (int t2 = 0; t2 < 8; ++t2){
        uint4 pu; pu.x = p[2 * t2].x; pu.y = p[2 * t2].y;
        pu.z = p[2 * t2 + 1].x; pu.w = p[2 * t2 + 1].y;
        short8 pf = __builtin_bit_cast(short8, pu);
        o0 = MFMA_BF16_K32(__builtin_bit_cast(short8, va[t2]), pf, o0);
        o1 = MFMA_BF16_K32(__builtin_bit_cast(short8, vb[t2]), pf, o1);
      }
      float invd = 1.0f / d;
      #pragma unroll
      for (int r = 0; r < 4; ++r){ res0[r] += o0[r] * invd; res1[r] += o1[r] * invd; }
    }
    if (qpos < Nn){
      size_t base = (bh * N2 + qpos) * 32;
      uint2 s0, s1;
      s0.x = cvtpk(res0[0], res0[1]); s0.y = cvtpk(res0[2], res0[3]);
      s1.x = cvtpk(res1[0], res1[1]); s1.y = cvtpk(res1[2], res1[3]);
      *reinterpret_cast<uint2*>(aoh + base + g4 * 4)      = s0;
      *reinterpret_cast<uint2*>(aoh + base + 16 + g4 * 4) = s1;
    }
  }
}

// ---- final: out[idx[b,j]] = attn[b,j] @ Wp^T, M=64 per block (FP32 out) ----
__global__ __launch_bounds__(256) void final_kernel(
    const ushort_t* __restrict__ A, const ushort_t* __restrict__ Wp,
    const int* __restrict__ idx, float* __restrict__ out)
{
  const int b  = blockIdx.y;
  const int r0 = blockIdx.x * 64;
  const int tid = threadIdx.x;
  const int w = tid >> 6, l = tid & 63, g4 = l >> 4, q16 = l & 15;
  f32x4 acc[4][4];
  #pragma unroll
  for (int mt = 0; mt < 4; ++mt)
    #pragma unroll
    for (int ct = 0; ct < 4; ++ct) acc[mt][ct] = f32x4{0.f, 0.f, 0.f, 0.f};
  const int colbase = w * 64;
  #pragma unroll
  for (int kc = 0; kc < 8; ++kc){
    short8 a[4];
    #pragma unroll
    for (int mt = 0; mt < 4; ++mt)
      a[mt] = *reinterpret_cast<const short8*>(
          A + ((size_t)(b * 8 + kc) * N2 + r0 + mt * 16 + q16) * 32 + g4 * 8);
    #pragma unroll
    for (int ct = 0; ct < 4; ++ct){
      int col = colbase + ct * 16 + q16;
      short8 bb = *reinterpret_cast<const short8*>(Wp + col * 256 + kc * 32 + g4 * 8);
      #pragma unroll
      for (int mt = 0; mt < 4; ++mt) acc[mt][ct] = MFMA_BF16_K32(a[mt], bb, acc[mt][ct]);
    }
  }
  #pragma unroll
  for (int mt = 0; mt < 4; ++mt){
    int orow[4];
    #pragma unroll
    for (int r = 0; r < 4; ++r) orow[r] = idx[b * Nn + r0 + mt * 16 + g4 * 4 + r];
    #pragma unroll
    for (int ct = 0; ct < 4; ++ct){
      int col = colbase + ct * 16 + q16;
      #pragma unroll
      for (int r = 0; r < 4; ++r)
        out[(size_t)(b * Nn + orow[r]) * DIMc + col] = acc[mt][ct][r];
    }
  }
}

extern "C" void kernel_launch(void* const* d_in, const int* in_sizes, int n_in,
                              void* d_out, int out_size, void* d_ws, size_t ws_size,
                              hipStream_t stream)
{
  const float* x   = (const float*)d_in[0];
  const int*   idx = (const int*)d_in[1];
  const float* kg  = (const float*)d_in[2];
  const float* vg  = (const float*)d_in[3];
  const float* Wq  = (const float*)d_in[4];
  const float* Wk  = (const float*)d_in[5];
  const float* Wv  = (const float*)d_in[6];
  const float* Wp  = (const float*)d_in[7];
  float* out = (float*)d_out;

  char* ws = (char*)d_ws;
  size_t off = 0;
  auto alloc = [&](size_t bytes) -> void* {
    void* p = ws + off; off += (bytes + 255) & ~(size_t)255; return p;
  };
  ushort_t* qh   = (ushort_t*)alloc((size_t)Bc * 8 * N2 * 16 * 2);
  ushort_t* kh   = (ushort_t*)alloc((size_t)Bc * 8 * N2 * 16 * 2);
  ushort_t* vT   = (ushort_t*)alloc((size_t)Bc * 256 * N2 * 2);
  ushort_t* aoh  = (ushort_t*)alloc((size_t)Bc * 8 * N2 * 32 * 2);
  ushort_t* Xb   = (ushort_t*)alloc((size_t)Bc * Nn * 256 * 2);
  ushort_t* Wc   = (ushort_t*)alloc((size_t)512 * 256 * 2);
  ushort_t* vgT  = (ushort_t*)alloc((size_t)8 * 32 * 256 * 2);
  ushort_t* kgb  = (ushort_t*)alloc((size_t)8 * 256 * 16 * 2);
  ushort_t* Wpb  = (ushort_t*)alloc((size_t)256 * 256 * 2);

  hipLaunchKernelGGL(cvt_x_kernel, dim3(8000), dim3(256), 0, stream, x, Xb);
  hipLaunchKernelGGL(prep_kernel,  dim3(1152), dim3(256), 0, stream,
                     Wq, Wk, Wv, Wp, kg, vg, Wc, vgT, kgb, Wpb);
  hipLaunchKernelGGL(proj_kernel,  dim3(125, 4), dim3(256), 0, stream, Xb, Wc, idx, qh, kh, vT);
  hipLaunchKernelGGL(reflect_fill_kernel, dim3(864), dim3(256), 0, stream, qh, kh, vT);
  hipLaunchKernelGGL(attn_kernel,  dim3(NG, 8, 4), dim3(256), 0, stream, qh, kh, vT, kgb, vgT, aoh);
  hipLaunchKernelGGL(final_kernel, dim3(125, 4), dim3(256), 0, stream, aoh, Wpb, idx, out);
}